// Round 1
// baseline (478.323 us; speedup 1.0000x reference)
//
#include <hip/hip_runtime.h>
#include <hip/hip_bf16.h>

#define S   64
#define NI  128
#define NT  192   // S + NI
#define WPB 4     // waves (rays) per block

__global__ __launch_bounds__(256) void nerf_fine_sample(
    const float* __restrict__ rays_o,
    const float* __restrict__ rays_d,
    const float* __restrict__ z_vals,
    const float* __restrict__ weights,
    float* __restrict__ out_pts,
    float* __restrict__ out_z)
{
    const int lane = threadIdx.x & 63;
    const int w    = threadIdx.x >> 6;
    const int ray  = blockIdx.x * WPB + w;

    __shared__ float s_zvals[WPB][S];
    __shared__ float s_zmid [WPB][S];    // 63 used
    __shared__ float s_cdf  [WPB][S];    // 63 used
    __shared__ float s_zs   [WPB][NI];
    __shared__ float s_zall [WPB][NT];
    __shared__ float s_od   [WPB][8];    // ox oy oz dx dy dz

    // ---- Phase 1: load + cdf/zmid ----
    const float zv = z_vals[(size_t)ray * S + lane];
    const float wt = weights[(size_t)ray * S + lane];
    s_zvals[w][lane] = zv;
    if (lane < 6) {
        s_od[w][lane] = (lane < 3) ? rays_o[(size_t)ray * 3 + lane]
                                   : rays_d[(size_t)ray * 3 + (lane - 3)];
    }

    // z_mid[i] = 0.5*(z[i] + z[i+1]), i in [0,62]
    float zvn = __shfl_down(zv, 1);
    if (lane < S - 1) s_zmid[w][lane] = 0.5f * (zv + zvn);

    // inclusive scan of x where x[k] = weights[k]+1e-5 for k in [1,62], else 0
    float x = (lane >= 1 && lane <= S - 2) ? (wt + 1e-5f) : 0.0f;
    float v = x;
    #pragma unroll
    for (int off = 1; off < 64; off <<= 1) {
        float n = __shfl_up(v, off);
        if (lane >= off) v += n;
    }
    const float total = __shfl(v, 63);
    const float inv   = 1.0f / total;
    if (lane <= S - 2) s_cdf[w][lane] = v * inv;   // cdf[0] = 0 (x[0]=0)

    __syncthreads();

    // ---- Phase 2: inverse-CDF sampling, 2 u's per lane ----
    {
        const float* cdf  = s_cdf[w];
        const float* zmid = s_zmid[w];
        const float step = 1.0f / 127.0f;
        #pragma unroll
        for (int r = 0; r < 2; ++r) {
            const int k = lane + r * 64;
            float u = (k == NI - 1) ? 1.0f : (float)k * step;
            // searchsorted(cdf[0..62], u, side='right') -> count of entries <= u
            int lo = 0, hi = S - 1;  // 63 entries
            while (lo < hi) {
                int m = (lo + hi) >> 1;
                if (cdf[m] <= u) lo = m + 1; else hi = m;
            }
            const int below = (lo > 0) ? lo - 1 : 0;
            const int above = (lo < S - 2) ? lo : S - 2;
            const float cb = cdf[below], ca = cdf[above];
            const float bb = zmid[below], ba = zmid[above];
            float denom = ca - cb;
            if (denom < 1e-5f) denom = 1.0f;
            const float t = (u - cb) / denom;
            s_zs[w][k] = bb + t * (ba - bb);
        }
    }
    __syncthreads();

    // ---- Phase 3: merge sorted z_vals (64) with sorted z_samples (128) ----
    // rank(A[i]) = i + |{B < A[i]}| ; rank(B[j]) = j + |{A <= B[j]}|
    {
        const float* zs = s_zs[w];
        int lo = 0, hi = NI;
        while (lo < hi) {
            int m = (lo + hi) >> 1;
            if (zs[m] < zv) lo = m + 1; else hi = m;
        }
        s_zall[w][lane + lo] = zv;
    }
    {
        const float* za = s_zvals[w];
        #pragma unroll
        for (int r = 0; r < 2; ++r) {
            const int j = lane + r * 64;
            const float z = s_zs[w][j];
            int lo = 0, hi = S;
            while (lo < hi) {
                int m = (lo + hi) >> 1;
                if (za[m] <= z) lo = m + 1; else hi = m;
            }
            s_zall[w][j + lo] = z;
        }
    }
    __syncthreads();

    // ---- Phase 4: coalesced vectorized writes ----
    const float ox = s_od[w][0], oy = s_od[w][1], oz = s_od[w][2];
    const float dx = s_od[w][3], dy = s_od[w][4], dz = s_od[w][5];

    // z_all: 192 floats = 48 float4 per ray
    if (lane < NT / 4) {
        float4 q = ((const float4*)s_zall[w])[lane];
        ((float4*)(out_z + (size_t)ray * NT))[lane] = q;
    }

    // pts: 576 floats = 144 float4 per ray
    float* po = out_pts + (size_t)ray * NT * 3;
    #pragma unroll
    for (int r = 0; r < 3; ++r) {
        const int e4 = lane + r * 64;
        if (e4 < 144) {
            float4 q;
            float qv[4];
            #pragma unroll
            for (int c = 0; c < 4; ++c) {
                const int e = e4 * 4 + c;
                const int s = e / 3;
                const int comp = e - 3 * s;
                const float z = s_zall[w][s];
                const float o = (comp == 0) ? ox : ((comp == 1) ? oy : oz);
                const float d = (comp == 0) ? dx : ((comp == 1) ? dy : dz);
                qv[c] = o + d * z;
            }
            q.x = qv[0]; q.y = qv[1]; q.z = qv[2]; q.w = qv[3];
            ((float4*)po)[e4] = q;
        }
    }
}

extern "C" void kernel_launch(void* const* d_in, const int* in_sizes, int n_in,
                              void* d_out, int out_size, void* d_ws, size_t ws_size,
                              hipStream_t stream) {
    const float* rays_o  = (const float*)d_in[0];
    const float* rays_d  = (const float*)d_in[1];
    const float* z_vals  = (const float*)d_in[2];
    const float* weights = (const float*)d_in[3];

    const int n_rays = in_sizes[0] / 3;          // 131072
    float* out_pts = (float*)d_out;              // [N, 192, 3]
    float* out_z   = out_pts + (size_t)n_rays * NT * 3;  // [N, 192]

    const int grid = n_rays / WPB;               // 32768, exact
    nerf_fine_sample<<<grid, 256, 0, stream>>>(rays_o, rays_d, z_vals, weights,
                                               out_pts, out_z);
}